// Round 11
// baseline (1515.657 us; speedup 1.0000x reference)
//
#include <hip/hip_runtime.h>
#include <stdint.h>

typedef _Float16 f16;
typedef _Float16 F16x8 __attribute__((ext_vector_type(8)));
typedef float F32x4 __attribute__((ext_vector_type(4)));

#define MFMA16(a,b,c) __builtin_amdgcn_mfma_f32_16x16x32_f16((a),(b),(c),0,0,0)
#define S12f 2.8853900817779268f    // 2*log2(e): folded into W1,W2,b1,b2
#define SABf (-1.4426950408889634f) // -log2(e): folded into Wa,Wb,ba,bb

// MUST be the builtin (inline-asm v_exp_f32 lacks TRANS-pipe hazard handling; r6/r7 failures)
static __device__ __forceinline__ float exp2_fast(float x){
  return __builtin_amdgcn_exp2f(x);
}
// prescaled pre-acts: a0=2log2e*p1, a1=2log2e*p2, a2+a3=-log2e*(pa+pb)
static __device__ __forceinline__ f16 cfc_act(F32x4 a){
  float e1=exp2_fast(a[0]);
  float e2=exp2_fast(a[1]);
  float es=exp2_fast(a[2]+a[3]);
  float f1=1.f-2.f*__builtin_amdgcn_rcpf(e1+1.f);
  float f2=1.f-2.f*__builtin_amdgcn_rcpf(e2+1.f);
  float s=__builtin_amdgcn_rcpf(1.f+es);
  return (f16)(f1+s*(f2-f1));
}
// frag-interleaved layout: value (k,b) at (k>>3)*128 + b*8 + (k&7); frag elem j of lane (g_l,b_l) = k = kt*32+g_l*8+j
static __device__ __forceinline__ int fidx(int k,int b){ return ((k>>3)<<7)+(b<<3)+(k&7); }

// ---------------- prep (byte-identical to r8/r9's validated version) ----------------
// H0 (Kpad=128): h0@0..115, dt@124(in-reg), one@125(in-reg). H1 (96): h1@0..75, one@88(in-reg). H2 (64): h2.
// tiles: L0: rt 0..28 x kt 0..3  -> rt*4+kt                 [0,116)
//        L1: rt 0..18 x kt 0..6  -> 116 + rt*7+kt           [116,249)
//        L2: rt 0..15 x kt 0..4  -> 249 + rt*5+kt           [249,329)
//        RO: rt 0..1  x kt 0..1  -> 329 + rt*2+kt           [329,333)
__global__ __launch_bounds__(256) void cfc_prep(
    const float* __restrict__ W10,const float* __restrict__ W20,const float* __restrict__ Wa0,const float* __restrict__ Wb0,
    const float* __restrict__ b10,const float* __restrict__ b20,const float* __restrict__ ba0,const float* __restrict__ bb0,
    const int* __restrict__ M0,
    const float* __restrict__ W11,const float* __restrict__ W21,const float* __restrict__ Wa1,const float* __restrict__ Wb1,
    const float* __restrict__ b11,const float* __restrict__ b21,const float* __restrict__ ba1,const float* __restrict__ bb1,
    const int* __restrict__ M1,
    const float* __restrict__ W12,const float* __restrict__ W22,const float* __restrict__ Wa2,const float* __restrict__ Wb2,
    const float* __restrict__ b12,const float* __restrict__ b22,const float* __restrict__ ba2,const float* __restrict__ bb2,
    const int* __restrict__ M2,
    const float* __restrict__ Wo, f16* __restrict__ ws)
{
  int idx=blockIdx.x*256+threadIdx.x;
  if(idx>=21312) return;
  int tile=idx>>6, lane=idx&63, ml=lane&15, grp=lane>>4;
  F16x8 fr;
  if(tile<329){
    int rt,kt,c,lay;
    const float *w1,*w2,*wa,*wb,*c1,*c2,*ca,*cb; const int* M;
    if(tile<116){ rt=tile>>2; kt=tile&3; c=117; lay=0;
      w1=W10;w2=W20;wa=Wa0;wb=Wb0;M=M0;c1=b10;c2=b20;ca=ba0;cb=bb0; }
    else if(tile<249){ int u=tile-116; rt=u/7; kt=u-rt*7; c=192; lay=1;
      w1=W11;w2=W21;wa=Wa1;wb=Wb1;M=M1;c1=b11;c2=b21;ca=ba1;cb=bb1; }
    else { int u=tile-249; rt=u/5; kt=u-rt*5; c=140; lay=2;
      w1=W12;w2=W22;wa=Wa2;wb=Wb2;M=M2;c1=b12;c2=b22;ca=ba2;cb=bb2; }
    int n=rt*4+(ml>>2), mat=ml&3;
    const float* W =(mat==0)?w1:(mat==1)?w2:(mat==2)?wa:wb;
    const float* Bv=(mat==0)?c1:(mat==1)?c2:(mat==2)?ca:cb;
    float sc=(mat<2)?S12f:SABf;
    int k0=kt*32+grp*8;
    #pragma unroll
    for(int j=0;j<8;++j){
      int k=k0+j; float v=0.f; int col=-1;
      if(lay==0){       // x=[dt@ref0, h0@ref1..116]; k<116->h0, k==124->dt, k==125->bias
        if(k<116) col=1+k; else if(k==124) col=0; else if(k==125) col=-2;
      } else if(lay==1){ // x=[h0(116), h1(76)]; k<116->h0, 128<=k<204->h1, k==125->bias
        if(k<116) col=k; else if(k>=128 && k<204) col=116+(k-128); else if(k==125) col=-2;
      } else {           // x=[h1(76), h2(64)]; k<76->h1, 96<=k<160->h2, k==88->bias
        if(k<76) col=k; else if(k>=96 && k<160) col=76+(k-96); else if(k==88) col=-2;
      }
      if(col>=0){ v=W[n*c+col]; if(mat<2) v*=(float)M[n*c+col]; }
      else if(col==-2){ v=Bv[n]; }
      fr[j]=(f16)(v*sc);
    }
  } else {
    int u=tile-329, rt=u>>1, kt=u&1;
    int o=rt*16+ml, k0=kt*32+grp*8;
    #pragma unroll
    for(int j=0;j<8;++j) fr[j]=(f16)Wo[o*64+k0+j];
  }
  ((F16x8*)ws)[idx]=fr;
}

// ---------------- main: wave-specialized systolic pipeline, ONE barrier per tick ----------------
// tick I (P=I&1): all groups read [P^1], write [P]:
//   G1 (waves 0-2):  h1(I-1) = L1(h0(I-1), h1(I-2))      active 1<=I<=1024
//   G0 (waves 3-5):  h0(I)   = L0(dt[I],  h0(I-1))       active I<=1023
//   G2 (waves 6-7):  h2(I-2) = L2(h1(I-2), h2(I-3))      active 2<=I<=1025
//   RO (waves 5,6):  y(I-3)  = h2(I-3) @ Wout + bout     active 3<=I<=1026
__global__ __launch_bounds__(512,1) void cfc_main(
    const float* __restrict__ dtp, const float* __restrict__ hxp,
    const float* __restrict__ boutp, const f16* __restrict__ ws, float* __restrict__ outp)
{
  const int tid=threadIdx.x, lane=tid&63, w=tid>>6;
  const int b_l=lane&15, g_l=lane>>4;
  const int gb0=blockIdx.x*16;
  const f16 onef=(f16)1.f;

  __shared__ alignas(16) f16 H0[2][2048];   // h0, Kpad=128 (cols 116..127 stay 0)
  __shared__ alignas(16) f16 H1[2][1536];   // h1, Kpad=96  (cols 76..95 stay 0)
  __shared__ alignas(16) f16 H2[2][1024];   // h2, K=64
  __shared__ f16 DTS[16384];                // [t][b] stride 16

  const F16x8* wsf=(const F16x8*)ws;

  // unified weight register array (static indexing only)
  F16x8 wl[50];
  F16x8 wro0, wro1;
  int nt;
  if(w<3){                       // G1: L1 tiles, rt=w+3j, 7 frags each
    nt=(w==0)?7:6;
    #pragma unroll
    for(int j=0;j<7;++j) if(j<nt){ int rt=w+3*j;
      #pragma unroll
      for(int kt=0;kt<7;++kt) wl[j*7+kt]=wsf[(116+rt*7+kt)*64+lane]; }
  } else if(w<6){                // G0: L0 tiles, rt=(w-3)+3j, 4 frags each
    int wi=w-3; nt=(wi<2)?10:9;
    #pragma unroll
    for(int j=0;j<10;++j) if(j<nt){ int rt=wi+3*j;
      #pragma unroll
      for(int kt=0;kt<4;++kt) wl[j*4+kt]=wsf[(rt*4+kt)*64+lane]; }
  } else {                       // G2: L2 tiles, rt=(w-6)+2j, 5 frags each
    nt=8; int wi=w-6;
    #pragma unroll
    for(int j=0;j<8;++j){ int rt=wi+2*j;
      #pragma unroll
      for(int kt=0;kt<5;++kt) wl[j*5+kt]=wsf[(249+rt*5+kt)*64+lane]; }
  }
  const bool isro=(w==5)||(w==6);
  F32x4 bias_ro; float* op=0;
  if(isro){ int rt=(w==5)?0:1;
    wro0=wsf[(329+rt*2+0)*64+lane];
    wro1=wsf[(329+rt*2+1)*64+lane];
    int o0=rt*16+g_l*4;
    bias_ro[0]=boutp[o0]; bias_ro[1]=boutp[o0+1]; bias_ro[2]=boutp[o0+2]; bias_ro[3]=boutp[o0+3];
    op=outp + (size_t)(gb0+b_l)*1024*32 + o0;
  }

  // ---- init: zero both parities, stage dt, load hx into BOTH parities ----
  for(int i=tid;i<4096;i+=512) ((f16*)H0)[i]=(f16)0.f;
  for(int i=tid;i<3072;i+=512) ((f16*)H1)[i]=(f16)0.f;
  for(int i=tid;i<2048;i+=512) ((f16*)H2)[i]=(f16)0.f;
  for(int i=tid;i<16384;i+=512){ int b=i>>10, t=i&1023; DTS[t*16+b]=(f16)dtp[(size_t)(gb0+b)*1024+t]; }
  __syncthreads();
  for(int i=tid;i<4096;i+=512){ int b=i>>8,u=i&255; f16 v=(f16)hxp[(size_t)(gb0+b)*256+u];
    if(u<116){ H0[0][fidx(u,b)]=v; H0[1][fidx(u,b)]=v; }
    else if(u<192){ int n=u-116; H1[0][fidx(n,b)]=v; H1[1][fidx(n,b)]=v; }
    else { int n=u-192; H2[0][fidx(n,b)]=v; H2[1][fidx(n,b)]=v; }
  }
  __syncthreads();

  for(int I=0;I<1028;++I){
    const int P=I&1;
    if(w<3){
      // ---------- G1: h1(I-1) ----------
      if(I>=1 && I<=1024){
        const F16x8* h0r=(const F16x8*)H0[P^1];
        const F16x8* h1r=(const F16x8*)H1[P^1];
        F16x8 Bf0=h0r[0*64+lane], Bf1=h0r[1*64+lane], Bf2=h0r[2*64+lane], Bf3=h0r[3*64+lane];
        F16x8 Bf4=h1r[0*64+lane], Bf5=h1r[1*64+lane], Bf6=h1r[2*64+lane];
        if(g_l==3) Bf3[5]=onef;                       // bias-one col k=125
        #pragma unroll
        for(int j=0;j<7;++j) if(j<nt){
          F32x4 a; a[0]=0.f;a[1]=0.f;a[2]=0.f;a[3]=0.f;
          a=MFMA16(wl[j*7+0],Bf0,a); a=MFMA16(wl[j*7+1],Bf1,a);
          a=MFMA16(wl[j*7+2],Bf2,a); a=MFMA16(wl[j*7+3],Bf3,a);
          a=MFMA16(wl[j*7+4],Bf4,a); a=MFMA16(wl[j*7+5],Bf5,a);
          a=MFMA16(wl[j*7+6],Bf6,a);
          int n=(w+3*j)*4+g_l;
          H1[P][fidx(n,b_l)]=cfc_act(a);
        }
      }
    } else if(w<6){
      // ---------- G0: h0(I) ----------
      if(I<=1023){
        const F16x8* h0r=(const F16x8*)H0[P^1];
        F16x8 Af0=h0r[0*64+lane], Af1=h0r[1*64+lane], Af2=h0r[2*64+lane], Af3=h0r[3*64+lane];
        f16 dtv=DTS[I*16+b_l];
        if(g_l==3){ Af3[4]=dtv; Af3[5]=onef; }        // dt@124, one@125
        #pragma unroll
        for(int j=0;j<10;++j) if(j<nt){
          F32x4 a; a[0]=0.f;a[1]=0.f;a[2]=0.f;a[3]=0.f;
          a=MFMA16(wl[j*4+0],Af0,a); a=MFMA16(wl[j*4+1],Af1,a);
          a=MFMA16(wl[j*4+2],Af2,a); a=MFMA16(wl[j*4+3],Af3,a);
          int n=((w-3)+3*j)*4+g_l;
          H0[P][fidx(n,b_l)]=cfc_act(a);
        }
      }
      if(w==5 && I>=3 && I<=1026){
        const F16x8* h2r=(const F16x8*)H2[P^1];
        F16x8 r0=h2r[0*64+lane], r1=h2r[1*64+lane];
        F32x4 r=bias_ro;
        r=MFMA16(wro0,r0,r); r=MFMA16(wro1,r1,r);
        *(F32x4*)op=r; op+=32;
      }
    } else {
      // ---------- G2: h2(I-2) ----------
      if(I>=2 && I<=1025){
        const F16x8* h1r=(const F16x8*)H1[P^1];
        const F16x8* h2r=(const F16x8*)H2[P^1];
        F16x8 Cf0=h1r[0*64+lane], Cf1=h1r[1*64+lane], Cf2=h1r[2*64+lane];
        F16x8 Cf3=h2r[0*64+lane], Cf4=h2r[1*64+lane];
        if(g_l==3) Cf2[0]=onef;                       // bias-one col k=88
        #pragma unroll
        for(int j=0;j<8;++j){
          F32x4 a; a[0]=0.f;a[1]=0.f;a[2]=0.f;a[3]=0.f;
          a=MFMA16(wl[j*5+0],Cf0,a); a=MFMA16(wl[j*5+1],Cf1,a);
          a=MFMA16(wl[j*5+2],Cf2,a); a=MFMA16(wl[j*5+3],Cf3,a);
          a=MFMA16(wl[j*5+4],Cf4,a);
          int n=((w-6)+2*j)*4+g_l;
          H2[P][fidx(n,b_l)]=cfc_act(a);
        }
      }
      if(w==6 && I>=3 && I<=1026){
        const F16x8* h2r=(const F16x8*)H2[P^1];
        F16x8 r0=h2r[0*64+lane], r1=h2r[1*64+lane];
        F32x4 r=bias_ro;
        r=MFMA16(wro0,r0,r); r=MFMA16(wro1,r1,r);
        *(F32x4*)op=r; op+=32;
      }
    }
    __syncthreads();
  }
}

extern "C" void kernel_launch(void* const* d_in, const int* in_sizes, int n_in,
                              void* d_out, int out_size, void* d_ws, size_t ws_size,
                              hipStream_t stream)
{
  (void)in_sizes; (void)n_in; (void)out_size; (void)ws_size;
  f16* ws=(f16*)d_ws;
  cfc_prep<<<84,256,0,stream>>>(
    (const float*)d_in[2],(const float*)d_in[3],(const float*)d_in[4],(const float*)d_in[5],
    (const float*)d_in[6],(const float*)d_in[7],(const float*)d_in[8],(const float*)d_in[9],
    (const int*)d_in[10],
    (const float*)d_in[11],(const float*)d_in[12],(const float*)d_in[13],(const float*)d_in[14],
    (const float*)d_in[15],(const float*)d_in[16],(const float*)d_in[17],(const float*)d_in[18],
    (const int*)d_in[19],
    (const float*)d_in[20],(const float*)d_in[21],(const float*)d_in[22],(const float*)d_in[23],
    (const float*)d_in[24],(const float*)d_in[25],(const float*)d_in[26],(const float*)d_in[27],
    (const int*)d_in[28],
    (const float*)d_in[29], ws);
  cfc_main<<<32,512,0,stream>>>(
    (const float*)d_in[0],(const float*)d_in[1],
    (const float*)d_in[30], ws, (float*)d_out);
}

// Round 12
// 1334.583 us; speedup vs baseline: 1.1357x; 1.1357x over previous
//
#include <hip/hip_runtime.h>
#include <stdint.h>

typedef _Float16 f16;
typedef _Float16 h2v __attribute__((ext_vector_type(2)));
typedef _Float16 F16x8 __attribute__((ext_vector_type(8)));
typedef float F32x4 __attribute__((ext_vector_type(4)));

#define MFMA16(a,b,c) __builtin_amdgcn_mfma_f32_16x16x32_f16((a),(b),(c),0,0,0)
#define S12f 2.8853900817779268f    // 2*log2(e): folded into W1,W2,b1,b2
#define SABf (-1.4426950408889634f) // -log2(e): folded into Wa,Wb,ba,bb

// builtin only (inline-asm v_exp_f32 lacks TRANS hazard handling; r6/r7 failures)
static __device__ __forceinline__ float exp2f_b(float x){ return __builtin_amdgcn_exp2f(x); }

// 4-trans act (vs 6): out = f1 + s*(f2-f1)
//  = 1 - 2*((E2+1)(1+es) - (E2-E1)) / ((E1+1)(E2+1)(1+es)),  E=exp2(prescaled), es=exp2(a2+a3)
// cancellation error bounded by ~2eps; args bounded |a|<~35 so no inf.
static __device__ __forceinline__ f16 cfc_act(F32x4 a){
  float E1=exp2f_b(a[0]), E2=exp2f_b(a[1]), es=exp2f_b(a[2]+a[3]);
  float t1=E1+1.f, u=(E2+1.f)*(1.f+es);
  float num=u-(E2-E1);
  float r=__builtin_amdgcn_rcpf(t1*u);
  return (f16)(1.f-2.f*num*r);
}
// frag-interleaved layout: value (k,b) at (k>>3)*128 + b*8 + (k&7)
static __device__ __forceinline__ int fidx(int k,int b){ return ((k>>3)<<7)+(b<<3)+(k&7); }

// ---------------- prep (byte-identical to r8/r11's validated version) ----------------
__global__ __launch_bounds__(256) void cfc_prep(
    const float* __restrict__ W10,const float* __restrict__ W20,const float* __restrict__ Wa0,const float* __restrict__ Wb0,
    const float* __restrict__ b10,const float* __restrict__ b20,const float* __restrict__ ba0,const float* __restrict__ bb0,
    const int* __restrict__ M0,
    const float* __restrict__ W11,const float* __restrict__ W21,const float* __restrict__ Wa1,const float* __restrict__ Wb1,
    const float* __restrict__ b11,const float* __restrict__ b21,const float* __restrict__ ba1,const float* __restrict__ bb1,
    const int* __restrict__ M1,
    const float* __restrict__ W12,const float* __restrict__ W22,const float* __restrict__ Wa2,const float* __restrict__ Wb2,
    const float* __restrict__ b12,const float* __restrict__ b22,const float* __restrict__ ba2,const float* __restrict__ bb2,
    const int* __restrict__ M2,
    const float* __restrict__ Wo, f16* __restrict__ ws)
{
  int idx=blockIdx.x*256+threadIdx.x;
  if(idx>=21312) return;
  int tile=idx>>6, lane=idx&63, ml=lane&15, grp=lane>>4;
  F16x8 fr;
  if(tile<329){
    int rt,kt,c,lay;
    const float *w1,*w2,*wa,*wb,*c1,*c2,*ca,*cb; const int* M;
    if(tile<116){ rt=tile>>2; kt=tile&3; c=117; lay=0;
      w1=W10;w2=W20;wa=Wa0;wb=Wb0;M=M0;c1=b10;c2=b20;ca=ba0;cb=bb0; }
    else if(tile<249){ int u=tile-116; rt=u/7; kt=u-rt*7; c=192; lay=1;
      w1=W11;w2=W21;wa=Wa1;wb=Wb1;M=M1;c1=b11;c2=b21;ca=ba1;cb=bb1; }
    else { int u=tile-249; rt=u/5; kt=u-rt*5; c=140; lay=2;
      w1=W12;w2=W22;wa=Wa2;wb=Wb2;M=M2;c1=b12;c2=b22;ca=ba2;cb=bb2; }
    int n=rt*4+(ml>>2), mat=ml&3;
    const float* W =(mat==0)?w1:(mat==1)?w2:(mat==2)?wa:wb;
    const float* Bv=(mat==0)?c1:(mat==1)?c2:(mat==2)?ca:cb;
    float sc=(mat<2)?S12f:SABf;
    int k0=kt*32+grp*8;
    #pragma unroll
    for(int j=0;j<8;++j){
      int k=k0+j; float v=0.f; int col=-1;
      if(lay==0){       if(k<116) col=1+k; else if(k==124) col=0; else if(k==125) col=-2; }
      else if(lay==1){  if(k<116) col=k; else if(k>=128 && k<204) col=116+(k-128); else if(k==125) col=-2; }
      else {            if(k<76) col=k; else if(k>=96 && k<160) col=76+(k-96); else if(k==88) col=-2; }
      if(col>=0){ v=W[n*c+col]; if(mat<2) v*=(float)M[n*c+col]; }
      else if(col==-2){ v=Bv[n]; }
      fr[j]=(f16)(v*sc);
    }
  } else {
    int u=tile-329, rt=u>>1, kt=u&1;
    int o=rt*16+ml, k0=kt*32+grp*8;
    #pragma unroll
    for(int j=0;j<8;++j) fr[j]=(f16)Wo[o*64+k0+j];
  }
  ((F16x8*)ws)[idx]=fr;
}

// ---------------- main: 32 WGs x 768 thr (12 waves, 3/SIMD); systolic 1-barrier; role-specialized loops ----------------
// tick I (P=I&1), all read [P^1], write [P]:
//   alpha w0-4 : 3 L1-tiles (h1(I-1), rt=3w+j) + 2 L0-tiles (h0(I), rt=2w+m)
//   beta  w5-8 : 1 L1-tile (rt=15+g)          + <=5 L0-tiles (rt=10+5g+m); w7,w8 stream XR->d_out (raw h2)
//   gamma w9-11: L2-tiles (h2(I-2); w9 rt0-5, w10 rt6-10, w11 rt11-15), dual-write H2 and XR
// readout deferred to cfc_ro (in-place d_out transform h2 -> y)
__global__ __launch_bounds__(768,1) void cfc_main(
    const float* __restrict__ dtp, const float* __restrict__ hxp,
    const f16* __restrict__ ws, float* __restrict__ outp)
{
  const int tid=threadIdx.x, lane=tid&63, w=tid>>6;
  const int b_l=lane&15, g_l=lane>>4;
  const int gb0=blockIdx.x*16;
  const f16 onef=(f16)1.f;

  __shared__ alignas(16) f16 H0[2][2048];   // h0, Kpad=128 (cols 116..127 stay 0; dt/one injected in-reg)
  __shared__ alignas(16) f16 H1[2][1536];   // h1, Kpad=96
  __shared__ alignas(16) f16 H2[2][1024];   // h2, K=64
  __shared__ alignas(16) f16 XR[2][1024];   // h2 copy for coalesced streaming
  __shared__ f16 DTS[16416];                // [t][b] stride 16, rows 1024..1025 zero

  const F16x8* wsf=(const F16x8*)ws;

  // ---- init ----
  for(int i=tid;i<4096;i+=768) ((f16*)H0)[i]=(f16)0.f;
  for(int i=tid;i<3072;i+=768) ((f16*)H1)[i]=(f16)0.f;
  for(int i=tid;i<2048;i+=768) ((f16*)H2)[i]=(f16)0.f;
  for(int i=tid;i<2048;i+=768) ((f16*)XR)[i]=(f16)0.f;
  for(int i=tid;i<16416;i+=768){
    int t=i>>4, b=i&15;
    DTS[i]=(t<1024)?(f16)dtp[(size_t)(gb0+b)*1024+t]:(f16)0.f;
  }
  __syncthreads();
  for(int i=tid;i<4096;i+=768){ int b=i>>8,u=i&255; f16 v=(f16)hxp[(size_t)(gb0+b)*256+u];
    if(u<116){ H0[0][fidx(u,b)]=v; H0[1][fidx(u,b)]=v; }
    else if(u<192){ int n=u-116; H1[0][fidx(n,b)]=v; H1[1][fidx(n,b)]=v; }
    else { int n=u-192; H2[0][fidx(n,b)]=v; H2[1][fidx(n,b)]=v; }
  }
  __syncthreads();

  if(w<5){
    // ================= alpha =================
    F16x8 wa[29];
    #pragma unroll
    for(int j=0;j<3;++j){ int rt=3*w+j;
      #pragma unroll
      for(int kt=0;kt<7;++kt) wa[j*7+kt]=wsf[(116+rt*7+kt)*64+lane]; }
    #pragma unroll
    for(int m=0;m<2;++m){ int rt=2*w+m;
      #pragma unroll
      for(int kt=0;kt<4;++kt) wa[21+m*4+kt]=wsf[(rt*4+kt)*64+lane]; }
    for(int I=0;I<1027;++I){
      const int P=I&1;
      if(I<=1024){
        F32x4 a1[3],a0[2];
        #pragma unroll
        for(int j=0;j<3;++j){a1[j][0]=0.f;a1[j][1]=0.f;a1[j][2]=0.f;a1[j][3]=0.f;}
        #pragma unroll
        for(int m=0;m<2;++m){a0[m][0]=0.f;a0[m][1]=0.f;a0[m][2]=0.f;a0[m][3]=0.f;}
        #pragma unroll
        for(int kt=0;kt<4;++kt){
          F16x8 Af=((const F16x8*)H0[P^1])[kt*64+lane];
          if(kt==3 && g_l==3){ Af[4]=DTS[I*16+b_l]; Af[5]=onef; }  // dt@124, one@125 (L1 wt there = 0/bias)
          a1[0]=MFMA16(wa[0*7+kt],Af,a1[0]);
          a1[1]=MFMA16(wa[1*7+kt],Af,a1[1]);
          a1[2]=MFMA16(wa[2*7+kt],Af,a1[2]);
          a0[0]=MFMA16(wa[21+0*4+kt],Af,a0[0]);
          a0[1]=MFMA16(wa[21+1*4+kt],Af,a0[1]);
        }
        #pragma unroll
        for(int kt=0;kt<3;++kt){
          F16x8 Hf=((const F16x8*)H1[P^1])[kt*64+lane];
          a1[0]=MFMA16(wa[0*7+4+kt],Hf,a1[0]);
          a1[1]=MFMA16(wa[1*7+4+kt],Hf,a1[1]);
          a1[2]=MFMA16(wa[2*7+4+kt],Hf,a1[2]);
        }
        if(I>=1){
          #pragma unroll
          for(int j=0;j<3;++j) H1[P][fidx((3*w+j)*4+g_l,b_l)]=cfc_act(a1[j]);
        }
        if(I<=1023){
          #pragma unroll
          for(int m=0;m<2;++m) H0[P][fidx((2*w+m)*4+g_l,b_l)]=cfc_act(a0[m]);
        }
      }
      __syncthreads();
    }
  } else if(w<9){
    // ================= beta =================
    const int g=w-5, nt0=(g<3)?5:4;
    F16x8 wb[27];
    { int rt=15+g;
      #pragma unroll
      for(int kt=0;kt<7;++kt) wb[kt]=wsf[(116+rt*7+kt)*64+lane]; }
    #pragma unroll
    for(int m=0;m<5;++m) if(m<nt0){ int rt=10+5*g+m;
      #pragma unroll
      for(int kt=0;kt<4;++kt) wb[7+m*4+kt]=wsf[(rt*4+kt)*64+lane]; }
    const bool dost=(w>=7);
    const int q=lane&7, bb=(lane>>3)+8*(w-7);
    char* outB=(char*)outp;
    for(int I=0;I<1027;++I){
      const int P=I&1;
      if(I<=1024){
        F32x4 a1,a0[5];
        a1[0]=0.f;a1[1]=0.f;a1[2]=0.f;a1[3]=0.f;
        #pragma unroll
        for(int m=0;m<5;++m){a0[m][0]=0.f;a0[m][1]=0.f;a0[m][2]=0.f;a0[m][3]=0.f;}
        #pragma unroll
        for(int kt=0;kt<4;++kt){
          F16x8 Af=((const F16x8*)H0[P^1])[kt*64+lane];
          if(kt==3 && g_l==3){ Af[4]=DTS[I*16+b_l]; Af[5]=onef; }
          a1=MFMA16(wb[kt],Af,a1);
          #pragma unroll
          for(int m=0;m<5;++m) if(m<nt0) a0[m]=MFMA16(wb[7+m*4+kt],Af,a0[m]);
        }
        #pragma unroll
        for(int kt=0;kt<3;++kt){
          F16x8 Hf=((const F16x8*)H1[P^1])[kt*64+lane];
          a1=MFMA16(wb[4+kt],Hf,a1);
        }
        if(I>=1) H1[P][fidx((15+g)*4+g_l,b_l)]=cfc_act(a1);
        if(I<=1023){
          #pragma unroll
          for(int m=0;m<5;++m) if(m<nt0) H0[P][fidx((10+5*g+m)*4+g_l,b_l)]=cfc_act(a0[m]);
        }
      }
      if(dost && I>=3){   // stream h2(I-3) raw into d_out slot (gb0+bb, I-3)
        F16x8 v=((const F16x8*)XR[P^1])[q*16+bb];
        size_t off=((size_t)((gb0+bb)*1024+(I-3)))*128 + q*16;
        *(F16x8*)(outB+off)=v;
      }
      __syncthreads();
    }
  } else {
    // ================= gamma =================
    const int g=w-9, nt2=(g==0)?6:5, base2=(g==0)?0:(6+5*(g-1));
    F16x8 wc[30];
    #pragma unroll
    for(int j=0;j<6;++j) if(j<nt2){ int rt=base2+j;
      #pragma unroll
      for(int kt=0;kt<5;++kt) wc[j*5+kt]=wsf[(249+rt*5+kt)*64+lane]; }
    for(int I=0;I<1027;++I){
      const int P=I&1;
      if(I>=2 && I<=1025){
        F16x8 Cf0=((const F16x8*)H1[P^1])[0*64+lane];
        F16x8 Cf1=((const F16x8*)H1[P^1])[1*64+lane];
        F16x8 Cf2=((const F16x8*)H1[P^1])[2*64+lane];
        F16x8 Cf3=((const F16x8*)H2[P^1])[0*64+lane];
        F16x8 Cf4=((const F16x8*)H2[P^1])[1*64+lane];
        if(g_l==3) Cf2[0]=onef;                       // one@88
        #pragma unroll
        for(int j=0;j<6;++j) if(j<nt2){
          F32x4 a; a[0]=0.f;a[1]=0.f;a[2]=0.f;a[3]=0.f;
          a=MFMA16(wc[j*5+0],Cf0,a); a=MFMA16(wc[j*5+1],Cf1,a);
          a=MFMA16(wc[j*5+2],Cf2,a); a=MFMA16(wc[j*5+3],Cf3,a);
          a=MFMA16(wc[j*5+4],Cf4,a);
          f16 hv=cfc_act(a);
          int n=(base2+j)*4+g_l;
          H2[P][fidx(n,b_l)]=hv;
          XR[P][fidx(n,b_l)]=hv;
        }
      }
      __syncthreads();
    }
  }
}

// ---------------- post: in-place d_out transform  h2(64 f16) -> y(32 f32) per (b,t) slot ----------------
__global__ __launch_bounds__(256) void cfc_ro(
    const float* __restrict__ Wo, const float* __restrict__ bo, float* __restrict__ outp)
{
  __shared__ h2v wT[1024];   // [kp][o]
  __shared__ float bs[32];
  int tid=threadIdx.x;
  for(int i=tid;i<1024;i+=256){ int kp=i>>5,o=i&31;
    h2v v; v[0]=(f16)Wo[o*64+2*kp]; v[1]=(f16)Wo[o*64+2*kp+1]; wT[i]=v; }
  if(tid<32) bs[tid]=bo[tid];
  __syncthreads();
  size_t s=(size_t)blockIdx.x*256+tid;      // 0..524287 = b*1024+t
  float* slot=outp+s*32;
  h2v x[32];
  #pragma unroll
  for(int r=0;r<8;++r) ((F16x8*)x)[r]=((const F16x8*)slot)[r];
  float y[32];
  #pragma unroll
  for(int o=0;o<32;++o){
    float acc=bs[o];
    #pragma unroll
    for(int kp=0;kp<32;++kp) acc=__builtin_amdgcn_fdot2(x[kp],wT[kp*32+o],acc,false);
    y[o]=acc;
  }
  #pragma unroll
  for(int r=0;r<8;++r) ((float4*)slot)[r]=((const float4*)y)[r];
}

extern "C" void kernel_launch(void* const* d_in, const int* in_sizes, int n_in,
                              void* d_out, int out_size, void* d_ws, size_t ws_size,
                              hipStream_t stream)
{
  (void)in_sizes; (void)n_in; (void)out_size; (void)ws_size;
  f16* ws=(f16*)d_ws;
  cfc_prep<<<84,256,0,stream>>>(
    (const float*)d_in[2],(const float*)d_in[3],(const float*)d_in[4],(const float*)d_in[5],
    (const float*)d_in[6],(const float*)d_in[7],(const float*)d_in[8],(const float*)d_in[9],
    (const int*)d_in[10],
    (const float*)d_in[11],(const float*)d_in[12],(const float*)d_in[13],(const float*)d_in[14],
    (const float*)d_in[15],(const float*)d_in[16],(const float*)d_in[17],(const float*)d_in[18],
    (const int*)d_in[19],
    (const float*)d_in[20],(const float*)d_in[21],(const float*)d_in[22],(const float*)d_in[23],
    (const float*)d_in[24],(const float*)d_in[25],(const float*)d_in[26],(const float*)d_in[27],
    (const int*)d_in[28],
    (const float*)d_in[29], ws);
  cfc_main<<<32,768,0,stream>>>(
    (const float*)d_in[0],(const float*)d_in[1], ws, (float*)d_out);
  cfc_ro<<<2048,256,0,stream>>>(
    (const float*)d_in[29],(const float*)d_in[30],(float*)d_out);
}

// Round 13
// 1246.910 us; speedup vs baseline: 1.2155x; 1.0703x over previous
//
#include <hip/hip_runtime.h>
#include <stdint.h>

typedef _Float16 f16;
typedef _Float16 h2v __attribute__((ext_vector_type(2)));
typedef _Float16 F16x8 __attribute__((ext_vector_type(8)));
typedef float F32x4 __attribute__((ext_vector_type(4)));

#define MFMA16(a,b,c) __builtin_amdgcn_mfma_f32_16x16x32_f16((a),(b),(c),0,0,0)
#define S12f 2.8853900817779268f    // 2*log2(e): folded into W1,W2,b1,b2
#define SABf (-1.4426950408889634f) // -log2(e): folded into Wa,Wb,ba,bb

// builtin only (inline-asm v_exp_f32 lacks TRANS hazard handling; r6/r7 failures)
static __device__ __forceinline__ float exp2f_b(float x){ return __builtin_amdgcn_exp2f(x); }

// 4-trans act: out = 1 - 2*((E2+1)(1+es) - (E2-E1)) / ((E1+1)(E2+1)(1+es))
static __device__ __forceinline__ f16 cfc_act(F32x4 a){
  float E1=exp2f_b(a[0]), E2=exp2f_b(a[1]), es=exp2f_b(a[2]+a[3]);
  float t1=E1+1.f, u=(E2+1.f)*(1.f+es);
  float num=u-(E2-E1);
  float r=__builtin_amdgcn_rcpf(t1*u);
  return (f16)(1.f-2.f*num*r);
}
// frag-interleaved layout: value (k,b) at (k>>3)*128 + b*8 + (k&7)
static __device__ __forceinline__ int fidx(int k,int b){ return ((k>>3)<<7)+(b<<3)+(k&7); }

// ---------------- prep (byte-identical to r8/r11/r12's validated version) ----------------
__global__ __launch_bounds__(256) void cfc_prep(
    const float* __restrict__ W10,const float* __restrict__ W20,const float* __restrict__ Wa0,const float* __restrict__ Wb0,
    const float* __restrict__ b10,const float* __restrict__ b20,const float* __restrict__ ba0,const float* __restrict__ bb0,
    const int* __restrict__ M0,
    const float* __restrict__ W11,const float* __restrict__ W21,const float* __restrict__ Wa1,const float* __restrict__ Wb1,
    const float* __restrict__ b11,const float* __restrict__ b21,const float* __restrict__ ba1,const float* __restrict__ bb1,
    const int* __restrict__ M1,
    const float* __restrict__ W12,const float* __restrict__ W22,const float* __restrict__ Wa2,const float* __restrict__ Wb2,
    const float* __restrict__ b12,const float* __restrict__ b22,const float* __restrict__ ba2,const float* __restrict__ bb2,
    const int* __restrict__ M2,
    const float* __restrict__ Wo, f16* __restrict__ ws)
{
  int idx=blockIdx.x*256+threadIdx.x;
  if(idx>=21312) return;
  int tile=idx>>6, lane=idx&63, ml=lane&15, grp=lane>>4;
  F16x8 fr;
  if(tile<329){
    int rt,kt,c,lay;
    const float *w1,*w2,*wa,*wb,*c1,*c2,*ca,*cb; const int* M;
    if(tile<116){ rt=tile>>2; kt=tile&3; c=117; lay=0;
      w1=W10;w2=W20;wa=Wa0;wb=Wb0;M=M0;c1=b10;c2=b20;ca=ba0;cb=bb0; }
    else if(tile<249){ int u=tile-116; rt=u/7; kt=u-rt*7; c=192; lay=1;
      w1=W11;w2=W21;wa=Wa1;wb=Wb1;M=M1;c1=b11;c2=b21;ca=ba1;cb=bb1; }
    else { int u=tile-249; rt=u/5; kt=u-rt*5; c=140; lay=2;
      w1=W12;w2=W22;wa=Wa2;wb=Wb2;M=M2;c1=b12;c2=b22;ca=ba2;cb=bb2; }
    int n=rt*4+(ml>>2), mat=ml&3;
    const float* W =(mat==0)?w1:(mat==1)?w2:(mat==2)?wa:wb;
    const float* Bv=(mat==0)?c1:(mat==1)?c2:(mat==2)?ca:cb;
    float sc=(mat<2)?S12f:SABf;
    int k0=kt*32+grp*8;
    #pragma unroll
    for(int j=0;j<8;++j){
      int k=k0+j; float v=0.f; int col=-1;
      if(lay==0){       if(k<116) col=1+k; else if(k==124) col=0; else if(k==125) col=-2; }
      else if(lay==1){  if(k<116) col=k; else if(k>=128 && k<204) col=116+(k-128); else if(k==125) col=-2; }
      else {            if(k<76) col=k; else if(k>=96 && k<160) col=76+(k-96); else if(k==88) col=-2; }
      if(col>=0){ v=W[n*c+col]; if(mat<2) v*=(float)M[n*c+col]; }
      else if(col==-2){ v=Bv[n]; }
      fr[j]=(f16)(v*sc);
    }
  } else {
    int u=tile-329, rt=u>>1, kt=u&1;
    int o=rt*16+ml, k0=kt*32+grp*8;
    #pragma unroll
    for(int j=0;j<8;++j) fr[j]=(f16)Wo[o*64+k0+j];
  }
  ((F16x8*)ws)[idx]=fr;
}

// ---------------- main: 32 WGs x 1024 thr (16 waves, 4/SIMD); systolic 1-barrier ----------------
// tick I (P=I&1), all read [P^1], write [P]:
//   w0-1  mixed: 2 L1 tiles (rt=2w+j) + 2 L0 tiles (rt=2w+m)   [shares H0 B-frags]
//   w2-6  L1 x3: rt = 4+3*(w-2)+j
//   w7-11 L0 x5: rt = 4+5*(w-7)+m ; w7,w8 also stream XR->d_out (raw h2(I-3))
//   w12-15 L2 x4: rt = 4*(w-12)+j ; dual-write H2 and XR
// readout deferred to cfc_ro (in-place d_out transform h2 -> y)
__global__ __launch_bounds__(1024,4) void cfc_main(
    const float* __restrict__ dtp, const float* __restrict__ hxp,
    const f16* __restrict__ ws, float* __restrict__ outp)
{
  const int tid=threadIdx.x, lane=tid&63, w=tid>>6;
  const int b_l=lane&15, g_l=lane>>4;
  const int gb0=blockIdx.x*16;
  const f16 onef=(f16)1.f;

  __shared__ alignas(16) f16 H0[2][2048];   // h0, Kpad=128 (dt@124/one@125 injected in-reg)
  __shared__ alignas(16) f16 H1[2][1536];   // h1, Kpad=96 (one@88 injected in-reg)
  __shared__ alignas(16) f16 H2[2][1024];   // h2, K=64
  __shared__ alignas(16) f16 XR[2][1024];   // h2 copy for coalesced streaming
  __shared__ f16 DTS[16416];                // [t][b] stride 16, rows 1024..1025 zero

  const F16x8* wsf=(const F16x8*)ws;

  // ---- init ----
  for(int i=tid;i<4096;i+=1024) ((f16*)H0)[i]=(f16)0.f;
  for(int i=tid;i<3072;i+=1024) ((f16*)H1)[i]=(f16)0.f;
  for(int i=tid;i<2048;i+=1024) ((f16*)H2)[i]=(f16)0.f;
  for(int i=tid;i<2048;i+=1024) ((f16*)XR)[i]=(f16)0.f;
  for(int i=tid;i<16416;i+=1024){
    int t=i>>4, b=i&15;
    DTS[i]=(t<1024)?(f16)dtp[(size_t)(gb0+b)*1024+t]:(f16)0.f;
  }
  __syncthreads();
  for(int i=tid;i<4096;i+=1024){ int b=i>>8,u=i&255; f16 v=(f16)hxp[(size_t)(gb0+b)*256+u];
    if(u<116){ H0[0][fidx(u,b)]=v; H0[1][fidx(u,b)]=v; }
    else if(u<192){ int n=u-116; H1[0][fidx(n,b)]=v; H1[1][fidx(n,b)]=v; }
    else { int n=u-192; H2[0][fidx(n,b)]=v; H2[1][fidx(n,b)]=v; }
  }
  __syncthreads();

  if(w<2){
    // ================= mixed: 2 L1 + 2 L0 =================
    F16x8 w1f[2][7], w0f[2][4];
    #pragma unroll
    for(int j=0;j<2;++j){ int rt=2*w+j;
      #pragma unroll
      for(int kt=0;kt<7;++kt) w1f[j][kt]=wsf[(116+rt*7+kt)*64+lane]; }
    #pragma unroll
    for(int m=0;m<2;++m){ int rt=2*w+m;
      #pragma unroll
      for(int kt=0;kt<4;++kt) w0f[m][kt]=wsf[(rt*4+kt)*64+lane]; }
    for(int I=0;I<1027;++I){
      const int P=I&1;
      if(I<=1024){
        F32x4 a1[2],a0[2];
        #pragma unroll
        for(int j=0;j<2;++j){a1[j][0]=0.f;a1[j][1]=0.f;a1[j][2]=0.f;a1[j][3]=0.f;
                             a0[j][0]=0.f;a0[j][1]=0.f;a0[j][2]=0.f;a0[j][3]=0.f;}
        #pragma unroll
        for(int kt=0;kt<4;++kt){
          F16x8 Af=((const F16x8*)H0[P^1])[kt*64+lane];
          if(kt==3 && g_l==3){ Af[4]=DTS[I*16+b_l]; Af[5]=onef; }
          a1[0]=MFMA16(w1f[0][kt],Af,a1[0]); a1[1]=MFMA16(w1f[1][kt],Af,a1[1]);
          a0[0]=MFMA16(w0f[0][kt],Af,a0[0]); a0[1]=MFMA16(w0f[1][kt],Af,a0[1]);
        }
        #pragma unroll
        for(int kt=0;kt<3;++kt){
          F16x8 Hf=((const F16x8*)H1[P^1])[kt*64+lane];
          a1[0]=MFMA16(w1f[0][4+kt],Hf,a1[0]); a1[1]=MFMA16(w1f[1][4+kt],Hf,a1[1]);
        }
        if(I>=1){
          #pragma unroll
          for(int j=0;j<2;++j) H1[P][fidx((2*w+j)*4+g_l,b_l)]=cfc_act(a1[j]);
        }
        if(I<=1023){
          #pragma unroll
          for(int m=0;m<2;++m) H0[P][fidx((2*w+m)*4+g_l,b_l)]=cfc_act(a0[m]);
        }
      }
      __syncthreads();
    }
  } else if(w<7){
    // ================= pure L1 x3 =================
    F16x8 wf[3][7];
    #pragma unroll
    for(int j=0;j<3;++j){ int rt=4+3*(w-2)+j;
      #pragma unroll
      for(int kt=0;kt<7;++kt) wf[j][kt]=wsf[(116+rt*7+kt)*64+lane]; }
    for(int I=0;I<1027;++I){
      const int P=I&1;
      if(I>=1 && I<=1024){
        F32x4 a1[3];
        #pragma unroll
        for(int j=0;j<3;++j){a1[j][0]=0.f;a1[j][1]=0.f;a1[j][2]=0.f;a1[j][3]=0.f;}
        #pragma unroll
        for(int kt=0;kt<4;++kt){
          F16x8 Af=((const F16x8*)H0[P^1])[kt*64+lane];
          if(kt==3 && g_l==3){ Af[4]=DTS[I*16+b_l]; Af[5]=onef; }
          a1[0]=MFMA16(wf[0][kt],Af,a1[0]); a1[1]=MFMA16(wf[1][kt],Af,a1[1]);
          a1[2]=MFMA16(wf[2][kt],Af,a1[2]);
        }
        #pragma unroll
        for(int kt=0;kt<3;++kt){
          F16x8 Hf=((const F16x8*)H1[P^1])[kt*64+lane];
          a1[0]=MFMA16(wf[0][4+kt],Hf,a1[0]); a1[1]=MFMA16(wf[1][4+kt],Hf,a1[1]);
          a1[2]=MFMA16(wf[2][4+kt],Hf,a1[2]);
        }
        #pragma unroll
        for(int j=0;j<3;++j) H1[P][fidx((4+3*(w-2)+j)*4+g_l,b_l)]=cfc_act(a1[j]);
      }
      __syncthreads();
    }
  } else if(w<12){
    // ================= pure L0 x5 (+XR streaming on w7,w8) =================
    F16x8 wf[5][4];
    #pragma unroll
    for(int m=0;m<5;++m){ int rt=4+5*(w-7)+m;
      #pragma unroll
      for(int kt=0;kt<4;++kt) wf[m][kt]=wsf[(rt*4+kt)*64+lane]; }
    const bool dost=(w<9);
    const int q=lane&7, bb=(lane>>3)+8*(w-7);
    char* outB=(char*)outp;
    for(int I=0;I<1027;++I){
      const int P=I&1;
      if(I<=1023){
        F32x4 a0[5];
        #pragma unroll
        for(int m=0;m<5;++m){a0[m][0]=0.f;a0[m][1]=0.f;a0[m][2]=0.f;a0[m][3]=0.f;}
        #pragma unroll
        for(int kt=0;kt<4;++kt){
          F16x8 Af=((const F16x8*)H0[P^1])[kt*64+lane];
          if(kt==3 && g_l==3){ Af[4]=DTS[I*16+b_l]; Af[5]=onef; }
          a0[0]=MFMA16(wf[0][kt],Af,a0[0]); a0[1]=MFMA16(wf[1][kt],Af,a0[1]);
          a0[2]=MFMA16(wf[2][kt],Af,a0[2]); a0[3]=MFMA16(wf[3][kt],Af,a0[3]);
          a0[4]=MFMA16(wf[4][kt],Af,a0[4]);
        }
        #pragma unroll
        for(int m=0;m<5;++m) H0[P][fidx((4+5*(w-7)+m)*4+g_l,b_l)]=cfc_act(a0[m]);
      }
      if(dost && I>=3){   // stream h2(I-3) raw into d_out slot (gb0+bb, I-3)
        F16x8 v=((const F16x8*)XR[P^1])[q*16+bb];
        size_t off=((size_t)((gb0+bb)*1024+(I-3)))*128 + q*16;
        *(F16x8*)(outB+off)=v;
      }
      __syncthreads();
    }
  } else {
    // ================= L2 x4 =================
    F16x8 wc[4][5];
    #pragma unroll
    for(int j=0;j<4;++j){ int rt=4*(w-12)+j;
      #pragma unroll
      for(int kt=0;kt<5;++kt) wc[j][kt]=wsf[(249+rt*5+kt)*64+lane]; }
    for(int I=0;I<1027;++I){
      const int P=I&1;
      if(I>=2 && I<=1025){
        F16x8 Cf0=((const F16x8*)H1[P^1])[0*64+lane];
        F16x8 Cf1=((const F16x8*)H1[P^1])[1*64+lane];
        F16x8 Cf2=((const F16x8*)H1[P^1])[2*64+lane];
        F16x8 Cf3=((const F16x8*)H2[P^1])[0*64+lane];
        F16x8 Cf4=((const F16x8*)H2[P^1])[1*64+lane];
        if(g_l==3) Cf2[0]=onef;                       // one@88
        #pragma unroll
        for(int j=0;j<4;++j){
          F32x4 a; a[0]=0.f;a[1]=0.f;a[2]=0.f;a[3]=0.f;
          a=MFMA16(wc[j][0],Cf0,a); a=MFMA16(wc[j][1],Cf1,a);
          a=MFMA16(wc[j][2],Cf2,a); a=MFMA16(wc[j][3],Cf3,a);
          a=MFMA16(wc[j][4],Cf4,a);
          f16 hv=cfc_act(a);
          int n=(4*(w-12)+j)*4+g_l;
          H2[P][fidx(n,b_l)]=hv;
          XR[P][fidx(n,b_l)]=hv;
        }
      }
      __syncthreads();
    }
  }
}

// ---------------- post: in-place d_out transform  h2(64 f16) -> y(32 f32) per (b,t) slot ----------------
__global__ __launch_bounds__(256) void cfc_ro(
    const float* __restrict__ Wo, const float* __restrict__ bo, float* __restrict__ outp)
{
  __shared__ h2v wT[1024];   // [kp][o]
  __shared__ float bs[32];
  int tid=threadIdx.x;
  for(int i=tid;i<1024;i+=256){ int kp=i>>5,o=i&31;
    h2v v; v[0]=(f16)Wo[o*64+2*kp]; v[1]=(f16)Wo[o*64+2*kp+1]; wT[i]=v; }
  if(tid<32) bs[tid]=bo[tid];
  __syncthreads();
  size_t s=(size_t)blockIdx.x*256+tid;      // 0..524287 = b*1024+t
  float* slot=outp+s*32;
  h2v x[32];
  #pragma unroll
  for(int r=0;r<8;++r) ((F16x8*)x)[r]=((const F16x8*)slot)[r];
  float y[32];
  #pragma unroll
  for(int o=0;o<32;++o){
    float acc=bs[o];
    #pragma unroll
    for(int kp=0;kp<32;++kp) acc=__builtin_amdgcn_fdot2(x[kp],wT[kp*32+o],acc,false);
    y[o]=acc;
  }
  #pragma unroll
  for(int r=0;r<8;++r) ((float4*)slot)[r]=((const float4*)y)[r];
}

extern "C" void kernel_launch(void* const* d_in, const int* in_sizes, int n_in,
                              void* d_out, int out_size, void* d_ws, size_t ws_size,
                              hipStream_t stream)
{
  (void)in_sizes; (void)n_in; (void)out_size; (void)ws_size;
  f16* ws=(f16*)d_ws;
  cfc_prep<<<84,256,0,stream>>>(
    (const float*)d_in[2],(const float*)d_in[3],(const float*)d_in[4],(const float*)d_in[5],
    (const float*)d_in[6],(const float*)d_in[7],(const float*)d_in[8],(const float*)d_in[9],
    (const int*)d_in[10],
    (const float*)d_in[11],(const float*)d_in[12],(const float*)d_in[13],(const float*)d_in[14],
    (const float*)d_in[15],(const float*)d_in[16],(const float*)d_in[17],(const float*)d_in[18],
    (const int*)d_in[19],
    (const float*)d_in[20],(const float*)d_in[21],(const float*)d_in[22],(const float*)d_in[23],
    (const float*)d_in[24],(const float*)d_in[25],(const float*)d_in[26],(const float*)d_in[27],
    (const int*)d_in[28],
    (const float*)d_in[29], ws);
  cfc_main<<<32,1024,0,stream>>>(
    (const float*)d_in[0],(const float*)d_in[1], ws, (float*)d_out);
  cfc_ro<<<2048,256,0,stream>>>(
    (const float*)d_in[29],(const float*)d_in[30],(float*)d_out);
}

// Round 14
// 1139.716 us; speedup vs baseline: 1.3299x; 1.0941x over previous
//
#include <hip/hip_runtime.h>
#include <stdint.h>

typedef _Float16 f16;
typedef _Float16 h2v __attribute__((ext_vector_type(2)));
typedef _Float16 F16x8 __attribute__((ext_vector_type(8)));
typedef float F32x4 __attribute__((ext_vector_type(4)));

#define MFMA16(a,b,c) __builtin_amdgcn_mfma_f32_16x16x32_f16((a),(b),(c),0,0,0)
#define S12f 2.8853900817779268f    // 2*log2(e): folded into W1,W2,b1,b2
#define SABf (-1.4426950408889634f) // -log2(e): folded into Wa,Wb,ba,bb

// builtin only (inline-asm v_exp_f32 lacks TRANS hazard handling; r6/r7 failures)
static __device__ __forceinline__ float exp2f_b(float x){ return __builtin_amdgcn_exp2f(x); }

// 4-trans act: out = 1 - 2*((E2+1)(1+es) - (E2-E1)) / ((E1+1)(E2+1)(1+es))
static __device__ __forceinline__ f16 cfc_act(F32x4 a){
  float E1=exp2f_b(a[0]), E2=exp2f_b(a[1]), es=exp2f_b(a[2]+a[3]);
  float t1=E1+1.f, u=(E2+1.f)*(1.f+es);
  float num=u-(E2-E1);
  float r=__builtin_amdgcn_rcpf(t1*u);
  return (f16)(1.f-2.f*num*r);
}
// frag-interleaved layout: value (k,b) at (k>>3)*128 + b*8 + (k&7)
static __device__ __forceinline__ int fidx(int k,int b){ return ((k>>3)<<7)+(b<<3)+(k&7); }

// ---------------- prep (byte-identical to r8/r11/r12/r13's validated version) ----------------
__global__ __launch_bounds__(256) void cfc_prep(
    const float* __restrict__ W10,const float* __restrict__ W20,const float* __restrict__ Wa0,const float* __restrict__ Wb0,
    const float* __restrict__ b10,const float* __restrict__ b20,const float* __restrict__ ba0,const float* __restrict__ bb0,
    const int* __restrict__ M0,
    const float* __restrict__ W11,const float* __restrict__ W21,const float* __restrict__ Wa1,const float* __restrict__ Wb1,
    const float* __restrict__ b11,const float* __restrict__ b21,const float* __restrict__ ba1,const float* __restrict__ bb1,
    const int* __restrict__ M1,
    const float* __restrict__ W12,const float* __restrict__ W22,const float* __restrict__ Wa2,const float* __restrict__ Wb2,
    const float* __restrict__ b12,const float* __restrict__ b22,const float* __restrict__ ba2,const float* __restrict__ bb2,
    const int* __restrict__ M2,
    const float* __restrict__ Wo, f16* __restrict__ ws)
{
  int idx=blockIdx.x*256+threadIdx.x;
  if(idx>=21312) return;
  int tile=idx>>6, lane=idx&63, ml=lane&15, grp=lane>>4;
  F16x8 fr;
  if(tile<329){
    int rt,kt,c,lay;
    const float *w1,*w2,*wa,*wb,*c1,*c2,*ca,*cb; const int* M;
    if(tile<116){ rt=tile>>2; kt=tile&3; c=117; lay=0;
      w1=W10;w2=W20;wa=Wa0;wb=Wb0;M=M0;c1=b10;c2=b20;ca=ba0;cb=bb0; }
    else if(tile<249){ int u=tile-116; rt=u/7; kt=u-rt*7; c=192; lay=1;
      w1=W11;w2=W21;wa=Wa1;wb=Wb1;M=M1;c1=b11;c2=b21;ca=ba1;cb=bb1; }
    else { int u=tile-249; rt=u/5; kt=u-rt*5; c=140; lay=2;
      w1=W12;w2=W22;wa=Wa2;wb=Wb2;M=M2;c1=b12;c2=b22;ca=ba2;cb=bb2; }
    int n=rt*4+(ml>>2), mat=ml&3;
    const float* W =(mat==0)?w1:(mat==1)?w2:(mat==2)?wa:wb;
    const float* Bv=(mat==0)?c1:(mat==1)?c2:(mat==2)?ca:cb;
    float sc=(mat<2)?S12f:SABf;
    int k0=kt*32+grp*8;
    #pragma unroll
    for(int j=0;j<8;++j){
      int k=k0+j; float v=0.f; int col=-1;
      if(lay==0){       if(k<116) col=1+k; else if(k==124) col=0; else if(k==125) col=-2; }
      else if(lay==1){  if(k<116) col=k; else if(k>=128 && k<204) col=116+(k-128); else if(k==125) col=-2; }
      else {            if(k<76) col=k; else if(k>=96 && k<160) col=76+(k-96); else if(k==88) col=-2; }
      if(col>=0){ v=W[n*c+col]; if(mat<2) v*=(float)M[n*c+col]; }
      else if(col==-2){ v=Bv[n]; }
      fr[j]=(f16)(v*sc);
    }
  } else {
    int u=tile-329, rt=u>>1, kt=u&1;
    int o=rt*16+ml, k0=kt*32+grp*8;
    #pragma unroll
    for(int j=0;j<8;++j) fr[j]=(f16)Wo[o*64+k0+j];
  }
  ((F16x8*)ws)[idx]=fr;
}

// ---------------- main: 32 WGs x 1024 thr (16 waves, 4/SIMD); systolic 1-barrier; tick-pair unrolled ----------------
// tick I (P=I&1, compile-time per unrolled body), all read [P^1], write [P]:
//   w0-1  mixed: 2 L1 tiles + 2 L0 tiles (shares H0 B-frags)
//   w2-6  L1 x3 ; w7-11 L0 x5 (w7,w8 stream H2[P^1] -> d_out raw h2(I-3))
//   w12-15 L2 x4 (single write to H2)
// readout deferred to cfc_ro (in-place d_out transform h2 -> y)
__global__ __launch_bounds__(1024,4) void cfc_main(
    const float* __restrict__ dtp, const float* __restrict__ hxp,
    const f16* __restrict__ ws, float* __restrict__ outp)
{
  const int tid=threadIdx.x, lane=tid&63, w=tid>>6;
  const int b_l=lane&15, g_l=lane>>4;
  const int gb0=blockIdx.x*16;
  const f16 onef=(f16)1.f;

  __shared__ alignas(16) f16 H0[2][2048];   // h0, Kpad=128 (dt@124/one@125 injected in-reg)
  __shared__ alignas(16) f16 H1[2][1536];   // h1, Kpad=96 (one@88 injected in-reg)
  __shared__ alignas(16) f16 H2[2][1024];   // h2, K=64 (also the streaming source)
  __shared__ f16 DTS[16448];                // [t][b] stride 16, rows 1024..1027 zero

  const F16x8* wsf=(const F16x8*)ws;

  // ---- init ----
  for(int i=tid;i<4096;i+=1024) ((f16*)H0)[i]=(f16)0.f;
  for(int i=tid;i<3072;i+=1024) ((f16*)H1)[i]=(f16)0.f;
  for(int i=tid;i<2048;i+=1024) ((f16*)H2)[i]=(f16)0.f;
  for(int i=tid;i<16448;i+=1024){
    int t=i>>4, b=i&15;
    DTS[i]=(t<1024)?(f16)dtp[(size_t)(gb0+b)*1024+t]:(f16)0.f;
  }
  __syncthreads();
  for(int i=tid;i<4096;i+=1024){ int b=i>>8,u=i&255; f16 v=(f16)hxp[(size_t)(gb0+b)*256+u];
    if(u<116){ H0[0][fidx(u,b)]=v; H0[1][fidx(u,b)]=v; }
    else if(u<192){ int n=u-116; H1[0][fidx(n,b)]=v; H1[1][fidx(n,b)]=v; }
    else { int n=u-192; H2[0][fidx(n,b)]=v; H2[1][fidx(n,b)]=v; }
  }
  __syncthreads();

  if(w<2){
    // ================= mixed: 2 L1 + 2 L0 =================
    F16x8 w1f[2][7], w0f[2][4];
    #pragma unroll
    for(int j=0;j<2;++j){ int rt=2*w+j;
      #pragma unroll
      for(int kt=0;kt<7;++kt) w1f[j][kt]=wsf[(116+rt*7+kt)*64+lane]; }
    #pragma unroll
    for(int m=0;m<2;++m){ int rt=2*w+m;
      #pragma unroll
      for(int kt=0;kt<4;++kt) w0f[m][kt]=wsf[(rt*4+kt)*64+lane]; }
    const int wb1a=fidx((2*w+0)*4+g_l,b_l), wb1b=fidx((2*w+1)*4+g_l,b_l);
    const int wb0a=fidx((2*w+0)*4+g_l,b_l), wb0b=fidx((2*w+1)*4+g_l,b_l);
#define MIXED_TICK(I_,P_) do{ \
      if((I_)<=1024){ \
        F32x4 a1_0,a1_1,a0_0,a0_1; \
        a1_0[0]=0.f;a1_0[1]=0.f;a1_0[2]=0.f;a1_0[3]=0.f; a1_1=a1_0; a0_0=a1_0; a0_1=a1_0; \
        _Pragma("unroll") \
        for(int kt=0;kt<4;++kt){ \
          F16x8 Af=((const F16x8*)H0[(P_)^1])[kt*64+lane]; \
          if(kt==3 && g_l==3){ Af[4]=DTS[(I_)*16+b_l]; Af[5]=onef; } \
          a1_0=MFMA16(w1f[0][kt],Af,a1_0); a1_1=MFMA16(w1f[1][kt],Af,a1_1); \
          a0_0=MFMA16(w0f[0][kt],Af,a0_0); a0_1=MFMA16(w0f[1][kt],Af,a0_1); \
        } \
        _Pragma("unroll") \
        for(int kt=0;kt<3;++kt){ \
          F16x8 Hf=((const F16x8*)H1[(P_)^1])[kt*64+lane]; \
          a1_0=MFMA16(w1f[0][4+kt],Hf,a1_0); a1_1=MFMA16(w1f[1][4+kt],Hf,a1_1); \
        } \
        if((I_)>=1){ H1[P_][wb1a]=cfc_act(a1_0); H1[P_][wb1b]=cfc_act(a1_1); } \
        if((I_)<=1023){ H0[P_][wb0a]=cfc_act(a0_0); H0[P_][wb0b]=cfc_act(a0_1); } \
      } }while(0)
    for(int I2=0;I2<1028;I2+=2){
      MIXED_TICK(I2,0);   __syncthreads();
      MIXED_TICK(I2+1,1); __syncthreads();
    }
#undef MIXED_TICK
  } else if(w<7){
    // ================= pure L1 x3 =================
    F16x8 wf[3][7];
    #pragma unroll
    for(int j=0;j<3;++j){ int rt=4+3*(w-2)+j;
      #pragma unroll
      for(int kt=0;kt<7;++kt) wf[j][kt]=wsf[(116+rt*7+kt)*64+lane]; }
    const int wb0=fidx((4+3*(w-2)+0)*4+g_l,b_l);
    const int wb1=fidx((4+3*(w-2)+1)*4+g_l,b_l);
    const int wb2=fidx((4+3*(w-2)+2)*4+g_l,b_l);
#define L1_TICK(I_,P_) do{ \
      if((I_)>=1 && (I_)<=1024){ \
        F32x4 a0,a1,a2; \
        a0[0]=0.f;a0[1]=0.f;a0[2]=0.f;a0[3]=0.f; a1=a0; a2=a0; \
        _Pragma("unroll") \
        for(int kt=0;kt<4;++kt){ \
          F16x8 Af=((const F16x8*)H0[(P_)^1])[kt*64+lane]; \
          if(kt==3 && g_l==3){ Af[4]=DTS[(I_)*16+b_l]; Af[5]=onef; } \
          a0=MFMA16(wf[0][kt],Af,a0); a1=MFMA16(wf[1][kt],Af,a1); a2=MFMA16(wf[2][kt],Af,a2); \
        } \
        _Pragma("unroll") \
        for(int kt=0;kt<3;++kt){ \
          F16x8 Hf=((const F16x8*)H1[(P_)^1])[kt*64+lane]; \
          a0=MFMA16(wf[0][4+kt],Hf,a0); a1=MFMA16(wf[1][4+kt],Hf,a1); a2=MFMA16(wf[2][4+kt],Hf,a2); \
        } \
        H1[P_][wb0]=cfc_act(a0); H1[P_][wb1]=cfc_act(a1); H1[P_][wb2]=cfc_act(a2); \
      } }while(0)
    for(int I2=0;I2<1028;I2+=2){
      L1_TICK(I2,0);   __syncthreads();
      L1_TICK(I2+1,1); __syncthreads();
    }
#undef L1_TICK
  } else if(w<12){
    // ================= pure L0 x5 (+streaming on w7,w8) =================
    F16x8 wf[5][4];
    #pragma unroll
    for(int m=0;m<5;++m){ int rt=4+5*(w-7)+m;
      #pragma unroll
      for(int kt=0;kt<4;++kt) wf[m][kt]=wsf[(rt*4+kt)*64+lane]; }
    int wbx[5];
    #pragma unroll
    for(int m=0;m<5;++m) wbx[m]=fidx((4+5*(w-7)+m)*4+g_l,b_l);
    const bool dost=(w<9);
    const int q=lane&7, bb=(lane>>3)+8*(w-7);
    char* outPtr=(char*)outp + ((size_t)(gb0+bb)*1024)*128 + q*16;
#define L0_TICK(I_,P_) do{ \
      if((I_)<=1023){ \
        F32x4 a0,a1,a2,a3,a4; \
        a0[0]=0.f;a0[1]=0.f;a0[2]=0.f;a0[3]=0.f; a1=a0; a2=a0; a3=a0; a4=a0; \
        _Pragma("unroll") \
        for(int kt=0;kt<4;++kt){ \
          F16x8 Af=((const F16x8*)H0[(P_)^1])[kt*64+lane]; \
          if(kt==3 && g_l==3){ Af[4]=DTS[(I_)*16+b_l]; Af[5]=onef; } \
          a0=MFMA16(wf[0][kt],Af,a0); a1=MFMA16(wf[1][kt],Af,a1); \
          a2=MFMA16(wf[2][kt],Af,a2); a3=MFMA16(wf[3][kt],Af,a3); \
          a4=MFMA16(wf[4][kt],Af,a4); \
        } \
        H0[P_][wbx[0]]=cfc_act(a0); H0[P_][wbx[1]]=cfc_act(a1); \
        H0[P_][wbx[2]]=cfc_act(a2); H0[P_][wbx[3]]=cfc_act(a3); \
        H0[P_][wbx[4]]=cfc_act(a4); \
      } \
      if(dost && (I_)>=3 && (I_)<=1026){ \
        F16x8 v=((const F16x8*)H2[(P_)^1])[q*16+bb]; \
        *(F16x8*)outPtr=v; outPtr+=128; \
      } }while(0)
    for(int I2=0;I2<1028;I2+=2){
      L0_TICK(I2,0);   __syncthreads();
      L0_TICK(I2+1,1); __syncthreads();
    }
#undef L0_TICK
  } else {
    // ================= L2 x4 =================
    F16x8 wc[4][5];
    #pragma unroll
    for(int j=0;j<4;++j){ int rt=4*(w-12)+j;
      #pragma unroll
      for(int kt=0;kt<5;++kt) wc[j][kt]=wsf[(249+rt*5+kt)*64+lane]; }
    int wbx[4];
    #pragma unroll
    for(int j=0;j<4;++j) wbx[j]=fidx((4*(w-12)+j)*4+g_l,b_l);
#define L2_TICK(I_,P_) do{ \
      if((I_)>=2 && (I_)<=1025){ \
        F16x8 Cf0=((const F16x8*)H1[(P_)^1])[0*64+lane]; \
        F16x8 Cf1=((const F16x8*)H1[(P_)^1])[1*64+lane]; \
        F16x8 Cf2=((const F16x8*)H1[(P_)^1])[2*64+lane]; \
        F16x8 Cf3=((const F16x8*)H2[(P_)^1])[0*64+lane]; \
        F16x8 Cf4=((const F16x8*)H2[(P_)^1])[1*64+lane]; \
        if(g_l==3) Cf2[0]=onef; \
        F32x4 a0,a1,a2,a3; \
        a0[0]=0.f;a0[1]=0.f;a0[2]=0.f;a0[3]=0.f; a1=a0; a2=a0; a3=a0; \
        a0=MFMA16(wc[0][0],Cf0,a0); a0=MFMA16(wc[0][1],Cf1,a0); a0=MFMA16(wc[0][2],Cf2,a0); \
        a0=MFMA16(wc[0][3],Cf3,a0); a0=MFMA16(wc[0][4],Cf4,a0); \
        a1=MFMA16(wc[1][0],Cf0,a1); a1=MFMA16(wc[1][1],Cf1,a1); a1=MFMA16(wc[1][2],Cf2,a1); \
        a1=MFMA16(wc[1][3],Cf3,a1); a1=MFMA16(wc[1][4],Cf4,a1); \
        a2=MFMA16(wc[2][0],Cf0,a2); a2=MFMA16(wc[2][1],Cf1,a2); a2=MFMA16(wc[2][2],Cf2,a2); \
        a2=MFMA16(wc[2][3],Cf3,a2); a2=MFMA16(wc[2][4],Cf4,a2); \
        a3=MFMA16(wc[3][0],Cf0,a3); a3=MFMA16(wc[3][1],Cf1,a3); a3=MFMA16(wc[3][2],Cf2,a3); \
        a3=MFMA16(wc[3][3],Cf3,a3); a3=MFMA16(wc[3][4],Cf4,a3); \
        H2[P_][wbx[0]]=cfc_act(a0); H2[P_][wbx[1]]=cfc_act(a1); \
        H2[P_][wbx[2]]=cfc_act(a2); H2[P_][wbx[3]]=cfc_act(a3); \
      } }while(0)
    for(int I2=0;I2<1028;I2+=2){
      L2_TICK(I2,0);   __syncthreads();
      L2_TICK(I2+1,1); __syncthreads();
    }
#undef L2_TICK
  }
}

// ---------------- post: in-place d_out transform  h2(64 f16) -> y(32 f32) per (b,t) slot ----------------
__global__ __launch_bounds__(256) void cfc_ro(
    const float* __restrict__ Wo, const float* __restrict__ bo, float* __restrict__ outp)
{
  __shared__ h2v wT[1024];   // [kp][o]
  __shared__ float bs[32];
  int tid=threadIdx.x;
  for(int i=tid;i<1024;i+=256){ int kp=i>>5,o=i&31;
    h2v v; v[0]=(f16)Wo[o*64+2*kp]; v[1]=(f16)Wo[o*64+2*kp+1]; wT[i]=v; }
  if(tid<32) bs[tid]=bo[tid];
  __syncthreads();
  size_t s=(size_t)blockIdx.x*256+tid;      // 0..524287 = b*1024+t
  float* slot=outp+s*32;
  h2v x[32];
  #pragma unroll
  for(int r=0;r<8;++r) ((F16x8*)x)[r]=((const F16x8*)slot)[r];
  float y[32];
  #pragma unroll
  for(int o=0;o<32;++o){
    float acc=bs[o];
    #pragma unroll
    for(int kp=0;kp<32;++kp) acc=__builtin_amdgcn_fdot2(x[kp],wT[kp*32+o],acc,false);
    y[o]=acc;
  }
  #pragma unroll
  for(int r=0;r<8;++r) ((float4*)slot)[r]=((const float4*)y)[r];
}

extern "C" void kernel_launch(void* const* d_in, const int* in_sizes, int n_in,
                              void* d_out, int out_size, void* d_ws, size_t ws_size,
                              hipStream_t stream)
{
  (void)in_sizes; (void)n_in; (void)out_size; (void)ws_size;
  f16* ws=(f16*)d_ws;
  cfc_prep<<<84,256,0,stream>>>(
    (const float*)d_in[2],(const float*)d_in[3],(const float*)d_in[4],(const float*)d_in[5],
    (const float*)d_in[6],(const float*)d_in[7],(const float*)d_in[8],(const float*)d_in[9],
    (const int*)d_in[10],
    (const float*)d_in[11],(const float*)d_in[12],(const float*)d_in[13],(const float*)d_in[14],
    (const float*)d_in[15],(const float*)d_in[16],(const float*)d_in[17],(const float*)d_in[18],
    (const int*)d_in[19],
    (const float*)d_in[20],(const float*)d_in[21],(const float*)d_in[22],(const float*)d_in[23],
    (const float*)d_in[24],(const float*)d_in[25],(const float*)d_in[26],(const float*)d_in[27],
    (const int*)d_in[28],
    (const float*)d_in[29], ws);
  cfc_main<<<32,1024,0,stream>>>(
    (const float*)d_in[0],(const float*)d_in[1], ws, (float*)d_out);
  cfc_ro<<<2048,256,0,stream>>>(
    (const float*)d_in[29],(const float*)d_in[30],(float*)d_out);
}